// Round 11
// baseline (192.500 us; speedup 1.0000x reference)
//
#include <hip/hip_runtime.h>
#include <math.h>

#define N_  2048
#define IN_ 400
#define C_  200
#define H_  256
#define M_  128
#define D_  8

#define KQ   224    // C_=200 padded to x32
#define KX   416    // IN_=400 padded to x32
#define KBIG 2112   // 2048 data + 8 bias + 56 pad (= 6*352, K-splittable x6)
#define NZ   6      // K-split of big GEMM
#define KSPL (KBIG / NZ)   // 352 = 11*32
#define KS   512    // [k | r] row stride

typedef __bf16 bf16x8 __attribute__((ext_vector_type(8)));
typedef float  f32x4  __attribute__((ext_vector_type(4)));

__device__ __forceinline__ ushort f2bf(float x) { __bf16 b = (__bf16)x; return __builtin_bit_cast(ushort, b); }
__device__ __forceinline__ float  bf2f(ushort u) { unsigned v = ((unsigned)u) << 16; return __builtin_bit_cast(float, v); }

__device__ __forceinline__ float4 f4z() { return make_float4(0.f, 0.f, 0.f, 0.f); }
__device__ __forceinline__ float4 ld4p(const float* p, bool v) { return v ? *(const float4*)p : f4z(); }
__device__ __forceinline__ float4 add4(float4 a, float4 b) {
    return make_float4(a.x + b.x, a.y + b.y, a.z + b.z, a.w + b.w);
}
__device__ __forceinline__ uint4 pack8(float4 a, float4 b) {
    ushort u[8] = { f2bf(a.x), f2bf(a.y), f2bf(a.z), f2bf(a.w),
                    f2bf(b.x), f2bf(b.y), f2bf(b.z), f2bf(b.w) };
    return *(uint4*)u;
}

// ---------------- double-buffered 128x64 MFMA GEMM core (staging via functor) ----
template<class F>
__device__ __forceinline__ void gemm_core(
    F&& ld, const float* __restrict__ bias,
    void* __restrict__ Cv, int ldc, int outbf,
    int m0, int n0, int kFrom, int kTo,
    ushort (*As)[128][40], ushort (*Bs)[64][40])
{
    const int tid = threadIdx.x, lane = tid & 63, wave = tid >> 6;
    const int wm = (wave >> 1) * 64, wn = (wave & 1) * 32;
    const int sr = tid >> 2, sc = (tid & 3) * 8;

    f32x4 acc[4][2] = {};

    auto compute = [&](int b) {
        const int ko = (lane >> 4) * 8;
        bf16x8 af[4], bfr[2];
#pragma unroll
        for (int i = 0; i < 4; i++)
            af[i] = __builtin_bit_cast(bf16x8, *(const uint4*)&As[b][wm + i * 16 + (lane & 15)][ko]);
#pragma unroll
        for (int j = 0; j < 2; j++)
            bfr[j] = __builtin_bit_cast(bf16x8, *(const uint4*)&Bs[b][wn + j * 16 + (lane & 15)][ko]);
#pragma unroll
        for (int i = 0; i < 4; i++)
#pragma unroll
            for (int j = 0; j < 2; j++)
                acc[i][j] = __builtin_amdgcn_mfma_f32_16x16x32_bf16(af[i], bfr[j], acc[i][j], 0, 0, 0);
    };

    uint4 a0, a1, b0;
    ld(kFrom, a0, a1, b0);
    *(uint4*)&As[0][sr][sc] = a0;
    *(uint4*)&As[0][sr + 64][sc] = a1;
    *(uint4*)&Bs[0][sr][sc] = b0;
    __syncthreads();

    int cur = 0;
    for (int k0 = kFrom + 32; k0 < kTo; k0 += 32) {
        ld(k0, a0, a1, b0);
        compute(cur);
        *(uint4*)&As[cur ^ 1][sr][sc] = a0;
        *(uint4*)&As[cur ^ 1][sr + 64][sc] = a1;
        *(uint4*)&Bs[cur ^ 1][sr][sc] = b0;
        __syncthreads();
        cur ^= 1;
    }
    compute(cur);

    float* Cf = (float*)Cv;
    ushort* Cb = (ushort*)Cv;
#pragma unroll
    for (int i = 0; i < 4; i++) {
#pragma unroll
        for (int j = 0; j < 2; j++) {
            int row = m0 + wm + i * 16 + (lane >> 4) * 4;
            int col = n0 + wn + j * 16 + (lane & 15);
#pragma unroll
            for (int r = 0; r < 4; r++) {
                float val = acc[i][j][r];
                if (bias) val += bias[col];
                if (outbf) Cb[(size_t)(row + r) * ldc + col] = f2bf(val);
                else       Cf[(size_t)(row + r) * ldc + col] = val;
            }
        }
    }
}

// ---------------- k1: z=0 k-GEMM, z=1 v-GEMM (inline f32->bf16), z>=2 Wcat repack ----
__global__ __launch_bounds__(256) void k1_kernel(
    const float* __restrict__ x,
    const float* __restrict__ ke_w, const float* __restrict__ ke_b, ushort* __restrict__ kr,
    const float* __restrict__ ve_w, const float* __restrict__ ve_b, float* __restrict__ v,
    const float* __restrict__ er_w, const float* __restrict__ er_b,
    const float* __restrict__ ad_w, const float* __restrict__ ad_b,
    ushort* __restrict__ wcat)
{
    __shared__ ushort As[2][128][40];
    __shared__ ushort Bs[2][64][40];
    const int z = blockIdx.z;
    const int sr = threadIdx.x >> 2, sc = (threadIdx.x & 3) * 8;

    if (z == 0) {
        const int m0 = blockIdx.y * 128, n0 = blockIdx.x * 64;
        auto ld = [&](int k0, uint4& A0, uint4& A1, uint4& B0) {
            int c0 = k0 + sc, c4 = c0 + 4;
            bool v0 = c0 < C_, v4 = c4 < C_;
            const float* r0 = x + (size_t)(m0 + sr) * IN_;
            const float* r1 = x + (size_t)(m0 + sr + 64) * IN_;
            A0 = pack8(add4(ld4p(r0 + c0, v0), ld4p(r0 + C_ + c0, v0)),
                       add4(ld4p(r0 + c4, v4), ld4p(r0 + C_ + c4, v4)));
            A1 = pack8(add4(ld4p(r1 + c0, v0), ld4p(r1 + C_ + c0, v0)),
                       add4(ld4p(r1 + c4, v4), ld4p(r1 + C_ + c4, v4)));
            const float* rb = ke_w + (size_t)(n0 + sr) * C_;
            B0 = pack8(ld4p(rb + c0, v0), ld4p(rb + c4, v4));
        };
        gemm_core(ld, ke_b, kr, KS, 1, m0, n0, 0, KQ, As, Bs);
    } else if (z == 1) {
        const int m0 = blockIdx.y * 128, n0 = blockIdx.x * 64;
        auto ld = [&](int k0, uint4& A0, uint4& A1, uint4& B0) {
            int c0 = k0 + sc, c4 = c0 + 4;
            bool v0 = c0 < IN_, v4 = c4 < IN_;
            const float* r0 = x + (size_t)(m0 + sr) * IN_;
            const float* r1 = x + (size_t)(m0 + sr + 64) * IN_;
            A0 = pack8(ld4p(r0 + c0, v0), ld4p(r0 + c4, v4));
            A1 = pack8(ld4p(r1 + c0, v0), ld4p(r1 + c4, v4));
            const float* rb = ve_w + (size_t)(n0 + sr) * IN_;
            B0 = pack8(ld4p(rb + c0, v0), ld4p(rb + c4, v4));
        };
        gemm_core(ld, ve_b, v, H_, 0, m0, n0, 0, KX, As, Bs);
    } else {
        int idx = ((z - 2) * 64 + blockIdx.y * 4 + blockIdx.x) * 256 + threadIdx.x;
        if (idx >= 512 * (KBIG / 4)) return;
        int oc = idx / (KBIG / 4), g = idx % (KBIG / 4), c0 = g * 4;
        const float* Wsrc = (oc < 256) ? er_w : ad_w;
        const float* bsrc = (oc < 256) ? er_b : ad_b;
        int oo = oc & 255;
        ushort pk[4];
#pragma unroll
        for (int j = 0; j < 4; j++) {
            int c = c0 + j;
            float val = 0.f;
            if (c < 2048)      { int d = c >> 8, ii = c & 255; val = Wsrc[(size_t)(d * 256 + oo) * 256 + ii]; }
            else if (c < 2056) { val = bsrc[(c - 2048) * 256 + oo]; }
            pk[j] = f2bf(val);
        }
        *(ushort4*)&wcat[(size_t)oc * KBIG + c0] = *(ushort4*)pk;
    }
}

// ---------------- vww: b<32 -> wlog GEMM (km_w inline cvt); else vw fill for n=b-32 ----
__global__ __launch_bounds__(256) void vww_kernel(
    const ushort* __restrict__ kr, const float* __restrict__ v,
    const float* __restrict__ kw2_w, const float* __restrict__ kw2_b,
    const float* __restrict__ km_w, const float* __restrict__ km_b,
    float* __restrict__ wlog, ushort* __restrict__ vw)
{
    __shared__ ushort As[2][128][40];
    __shared__ ushort Bs[2][64][40];
    __shared__ float kf[H_], vl[H_], lg[8], w2l[8];
    const int b = blockIdx.x, t = threadIdx.x;
    const int sr = t >> 2, sc = (t & 3) * 8;

    if (b < 32) {
        const int m0 = (b >> 1) * 128, n0 = (b & 1) * 64;
        auto ld = [&](int k0, uint4& A0, uint4& A1, uint4& B0) {
            A0 = *(const uint4*)&kr[(size_t)(m0 + sr) * KS + k0 + sc];
            A1 = *(const uint4*)&kr[(size_t)(m0 + sr + 64) * KS + k0 + sc];
            int c0 = k0 + sc, c4 = c0 + 4;
            const float* rb = km_w + (size_t)(n0 + sr) * H_;
            B0 = pack8(*(const float4*)(rb + c0), *(const float4*)(rb + c4));
        };
        gemm_core(ld, km_b, wlog, M_, 0, m0, n0, 0, H_, As, Bs);
        return;
    }

    const int n = b - 32;
    if (t < 64) {
        ushort4 u = ((const ushort4*)(kr + (size_t)n * KS))[t];
        kf[t * 4 + 0] = bf2f(u.x); kf[t * 4 + 1] = bf2f(u.y);
        kf[t * 4 + 2] = bf2f(u.z); kf[t * 4 + 3] = bf2f(u.w);
        float4 vv = ((const float4*)(v + (size_t)n * H_))[t];
        vl[t * 4 + 0] = vv.x; vl[t * 4 + 1] = vv.y;
        vl[t * 4 + 2] = vv.z; vl[t * 4 + 3] = vv.w;
    }
    __syncthreads();
    {
        int d = t >> 5, l = t & 31;
        float acc = 0.f;
        const float* wr = kw2_w + d * H_;
#pragma unroll
        for (int s = 0; s < 8; s++) acc += kf[l + 32 * s] * wr[l + 32 * s];
#pragma unroll
        for (int off = 16; off; off >>= 1) acc += __shfl_xor(acc, off);
        if (l == 0) lg[d] = acc + kw2_b[d];
    }
    __syncthreads();
    if (t < 8) {
        float val = lg[t];
        float mx = val;
#pragma unroll
        for (int off = 1; off < 8; off <<= 1) mx = fmaxf(mx, __shfl_xor(mx, off));
        float e = expf(val - mx), s = e;
#pragma unroll
        for (int off = 1; off < 8; off <<= 1) s += __shfl_xor(s, off);
        w2l[t] = e / s;
    }
    __syncthreads();
    ushort* row = vw + (size_t)n * KBIG;
    for (int g = t; g < KBIG / 4; g += 256) {
        int c0 = g * 4;
        ushort pk[4];
#pragma unroll
        for (int j = 0; j < 4; j++) {
            int c = c0 + j;
            float val = 0.f;
            if (c < 2048)      val = w2l[c >> 8] * vl[c & 255];
            else if (c < 2056) val = w2l[c - 2048];
            pk[j] = f2bf(val);
        }
        *(ushort4*)&row[c0] = *(ushort4*)pk;
    }
}

// ---------------- bigw: big expert GEMM, K split x NZ ----------------
__global__ __launch_bounds__(256) void bigw_kernel(
    const ushort* __restrict__ vw, const ushort* __restrict__ Wcat,
    float* __restrict__ parts)
{
    __shared__ ushort As[2][128][40];
    __shared__ ushort Bs[2][64][40];
    const int z = blockIdx.z;
    const int m0 = blockIdx.y * 128, n0 = blockIdx.x * 64;
    const int sr = threadIdx.x >> 2, sc = (threadIdx.x & 3) * 8;
    auto ld = [&](int k0, uint4& A0, uint4& A1, uint4& B0) {
        A0 = *(const uint4*)&vw[(size_t)(m0 + sr) * KBIG + k0 + sc];
        A1 = *(const uint4*)&vw[(size_t)(m0 + sr + 64) * KBIG + k0 + sc];
        B0 = *(const uint4*)&Wcat[(size_t)(n0 + sr) * KBIG + k0 + sc];
    };
    gemm_core(ld, nullptr, parts + (size_t)z * N_ * 512, 512, 0,
              m0, n0, z * KSPL, (z + 1) * KSPL, As, Bs);
}

// ---------------- eaw: per-n parts-sum -> e,a ; softmax(wlog) -> wbuf ----------------
__global__ __launch_bounds__(256) void eaw_kernel(
    const float* __restrict__ wlog, const float* __restrict__ parts,
    float* __restrict__ wbuf, float* __restrict__ ebuf, float* __restrict__ abuf)
{
    __shared__ float red[4];
    const int n = blockIdx.x, t = threadIdx.x;

    float s0 = 0.f, s1 = 0.f;
#pragma unroll
    for (int z = 0; z < NZ; z++) {
        s0 += parts[(size_t)z * N_ * 512 + (size_t)n * 512 + t];
        s1 += parts[(size_t)z * N_ * 512 + (size_t)n * 512 + 256 + t];
    }
    ebuf[(size_t)n * H_ + t] = 1.f / (1.f + expf(-s0));
    abuf[(size_t)n * H_ + t] = tanhf(s1);

    float lv = 0.f;
    if (t < 128) {
        lv = wlog[(size_t)n * M_ + t];
        float mx = lv;
#pragma unroll
        for (int off = 32; off; off >>= 1) mx = fmaxf(mx, __shfl_xor(mx, off));
        if ((t & 63) == 0) red[t >> 6] = mx;
    }
    __syncthreads();
    if (t < 128) {
        float gmax = fmaxf(red[0], red[1]);
        float ev = expf(lv - gmax);
        float s = ev;
#pragma unroll
        for (int off = 32; off; off >>= 1) s += __shfl_xor(s, off);
        if ((t & 63) == 0) red[2 + (t >> 6)] = s;
        __syncthreads();
        wbuf[(size_t)n * M_ + t] = ev / (red[2] + red[3]);
    }
}

// ---------------- mem stream: grid-stride groups, 32 consecutive rows/group ----------
// 2048 blocks x 256 thr = 16384 half-wave groups. Group g: n = g>>3,
// h in [(g&7)*32, +32). wv hoisted (one 16B load per group). Per row:
// NT load f32x4, fma, NT store, dot, 5-shuffle reduce, 2B kr store.
// Rows are independent -> compiler pipelines loads across iterations.
__global__ __launch_bounds__(256) void mem_stream_kernel(
    const float* __restrict__ mem_in,
    const float* __restrict__ wbuf, const float* __restrict__ ebuf,
    const float* __restrict__ abuf,
    float* __restrict__ mem_out, ushort* __restrict__ kr)
{
    const int gt = blockIdx.x * 256 + threadIdx.x;
    const int g = gt >> 5, l32 = gt & 31;
    const int n = g >> 3, h0 = (g & 7) * 32;

    f32x4 wv = ((const f32x4*)wbuf)[(n << 5) + l32];
    const f32x4* min4 = (const f32x4*)mem_in + ((size_t)(n << 8) + h0) * 32 + l32;
    f32x4* mout4 = (f32x4*)mem_out + ((size_t)(n << 8) + h0) * 32 + l32;
    const float* eb = ebuf + (n << 8) + h0;
    const float* ab = abuf + (n << 8) + h0;
    ushort* krow = kr + (size_t)n * KS + H_ + h0;

#pragma unroll 4
    for (int i = 0; i < 32; i++) {
        f32x4 mv = __builtin_nontemporal_load(&min4[i * 32]);
        float eh = eb[i], ah = ab[i];
        f32x4 nv = mv * (1.f - wv * eh) + wv * ah;
        __builtin_nontemporal_store(nv, &mout4[i * 32]);
        float r = mv[0] * wv[0] + mv[1] * wv[1] + mv[2] * wv[2] + mv[3] * wv[3];
#pragma unroll
        for (int off = 1; off < 32; off <<= 1) r += __shfl_xor(r, off);
        if (l32 == 0) krow[i] = f2bf(r);
    }
}

// ---------------- fy: f = tanh(kr @ sum_w.T + sum_b) fused into y ----------------
__global__ __launch_bounds__(256) void fy_kernel(
    const ushort* __restrict__ kr, const float* __restrict__ sum_w,
    const float* __restrict__ sum_b, const float* __restrict__ out_w,
    const float* __restrict__ out_b, float* __restrict__ y)
{
    __shared__ ushort As[2][64][40];
    __shared__ ushort Bs[2][256][40];
    __shared__ float yl[64][4];
    const int tid = threadIdx.x, lane = tid & 63, wave = tid >> 6;
    const int wn = wave * 64;
    const int m0 = blockIdx.x * 64;
    const int sr = tid >> 2, sc = (tid & 3) * 8;

    f32x4 acc[4][4] = {};

    auto compute = [&](int b) {
        const int ko = (lane >> 4) * 8;
        bf16x8 af[4], bfr[4];
#pragma unroll
        for (int i = 0; i < 4; i++)
            af[i] = __builtin_bit_cast(bf16x8, *(const uint4*)&As[b][i * 16 + (lane & 15)][ko]);
#pragma unroll
        for (int j = 0; j < 4; j++)
            bfr[j] = __builtin_bit_cast(bf16x8, *(const uint4*)&Bs[b][wn + j * 16 + (lane & 15)][ko]);
#pragma unroll
        for (int i = 0; i < 4; i++)
#pragma unroll
            for (int j = 0; j < 4; j++)
                acc[i][j] = __builtin_amdgcn_mfma_f32_16x16x32_bf16(af[i], bfr[j], acc[i][j], 0, 0, 0);
    };

    auto stage = [&](int buf, int k0) {
        int c0 = k0 + sc, c4 = c0 + 4;
        *(uint4*)&As[buf][sr][sc] = *(const uint4*)&kr[(size_t)(m0 + sr) * KS + k0 + sc];
#pragma unroll
        for (int g = 0; g < 4; g++) {
            const float* rb = sum_w + (size_t)(sr + g * 64) * KS;
            *(uint4*)&Bs[buf][sr + g * 64][sc] = pack8(*(const float4*)(rb + c0), *(const float4*)(rb + c4));
        }
    };

    stage(0, 0);
    __syncthreads();
    int cur = 0;
    for (int k0 = 32; k0 < KS; k0 += 32) {
        compute(cur);
        stage(cur ^ 1, k0);
        __syncthreads();
        cur ^= 1;
    }
    compute(cur);

    float ow[4], sb[4];
#pragma unroll
    for (int j = 0; j < 4; j++) {
        int col = wn + j * 16 + (lane & 15);
        ow[j] = out_w[col];
        sb[j] = sum_b[col];
    }
    float yp[4][4];
#pragma unroll
    for (int i = 0; i < 4; i++)
#pragma unroll
        for (int r = 0; r < 4; r++) {
            float s = 0.f;
#pragma unroll
            for (int j = 0; j < 4; j++)
                s += tanhf(acc[i][j][r] + sb[j]) * ow[j];
            yp[i][r] = s;
        }
#pragma unroll
    for (int off = 1; off < 16; off <<= 1)
#pragma unroll
        for (int i = 0; i < 4; i++)
#pragma unroll
            for (int r = 0; r < 4; r++)
                yp[i][r] += __shfl_xor(yp[i][r], off);
    if ((lane & 15) == 0) {
#pragma unroll
        for (int i = 0; i < 4; i++)
#pragma unroll
            for (int r = 0; r < 4; r++)
                yl[i * 16 + (lane >> 4) * 4 + r][wave] = yp[i][r];
    }
    __syncthreads();
    if (tid < 64)
        y[m0 + tid] = yl[tid][0] + yl[tid][1] + yl[tid][2] + yl[tid][3] + out_b[0];
}

extern "C" void kernel_launch(void* const* d_in, const int* in_sizes, int n_in,
                              void* d_out, int out_size, void* d_ws, size_t ws_size,
                              hipStream_t stream) {
    const float* x      = (const float*)d_in[0];
    const float* mem_in = (const float*)d_in[1];
    const float* ke_w   = (const float*)d_in[2];
    const float* ke_b   = (const float*)d_in[3];
    const float* km_w   = (const float*)d_in[4];
    const float* km_b   = (const float*)d_in[5];
    const float* kw2_w  = (const float*)d_in[6];
    const float* kw2_b  = (const float*)d_in[7];
    const float* sum_w  = (const float*)d_in[8];
    const float* sum_b  = (const float*)d_in[9];
    const float* out_w  = (const float*)d_in[10];
    const float* out_b  = (const float*)d_in[11];
    const float* ve_w   = (const float*)d_in[12];
    const float* ve_b   = (const float*)d_in[13];
    const float* er_w   = (const float*)d_in[14];
    const float* er_b   = (const float*)d_in[15];
    const float* ad_w   = (const float*)d_in[16];
    const float* ad_b   = (const float*)d_in[17];

    float* y_out   = (float*)d_out;
    float* mem_out = (float*)d_out + N_;

    // ---- workspace (float units, 16B-aligned offsets), ~46 MB ----
    float* ws = (float*)d_ws;
    size_t o = 0;
    float*  parts = ws + o;            o += (size_t)NZ * N_ * 512;      // 6,291,456
    ushort* vw    = (ushort*)(ws + o); o += (size_t)N_ * KBIG / 2;      // 2,162,688
    ushort* Wcat  = (ushort*)(ws + o); o += (size_t)512 * KBIG / 2;     //   540,672
    ushort* kr    = (ushort*)(ws + o); o += (size_t)N_ * KS / 2;        //   524,288
    float*  v     = ws + o;            o += (size_t)N_ * H_;            //   524,288
    float*  wlog  = ws + o;            o += (size_t)N_ * M_;            //   262,144
    float*  wbuf  = ws + o;            o += (size_t)N_ * M_;            //   262,144
    float*  ebuf  = ws + o;            o += (size_t)N_ * H_;            //   524,288
    float*  abuf  = ws + o;            o += (size_t)N_ * H_;            //   524,288

    // 1. k-GEMM (z=0) + v-GEMM (z=1) + Wcat repack (z=2..18), inline f32->bf16
    k1_kernel<<<dim3(4, 16, 19), 256, 0, stream>>>(
        x, ke_w, ke_b, kr, ve_w, ve_b, v, er_w, er_b, ad_w, ad_b, Wcat);
    // 2. wlog GEMM (b<32) + w2/vw fill (b>=32)
    vww_kernel<<<32 + N_, 256, 0, stream>>>(
        kr, v, kw2_w, kw2_b, km_w, km_b, wlog, vw);
    // 3. big expert GEMM, K split x6 -> 768 blocks
    bigw_kernel<<<dim3(8, 16, NZ), 256, 0, stream>>>(vw, Wcat, parts);
    // 4. gates: e/a from parts, w = softmax(wlog)
    eaw_kernel<<<N_, 256, 0, stream>>>(wlog, parts, wbuf, ebuf, abuf);
    // 5. stream: 2048 blocks, 32 consecutive rows per half-wave group, NT ld/st
    mem_stream_kernel<<<2048, 256, 0, stream>>>(
        mem_in, wbuf, ebuf, abuf, mem_out, kr);
    // 6. f GEMM fused with y reduction
    fy_kernel<<<N_ / 64, 256, 0, stream>>>(kr, sum_w, sum_b, out_w, out_b, y_out);
}

// Round 12
// 179.549 us; speedup vs baseline: 1.0721x; 1.0721x over previous
//
#include <hip/hip_runtime.h>
#include <math.h>

#define N_  2048
#define IN_ 400
#define C_  200
#define H_  256
#define M_  128
#define D_  8

#define KQ   224    // C_=200 padded to x32
#define KX   416    // IN_=400 padded to x32
#define KBIG 2112   // 2048 data + 8 bias + 56 pad (= 6*352, K-splittable x6)
#define NZ   6      // K-split of big GEMM
#define KSPL (KBIG / NZ)   // 352 = 11*32
#define KS   512    // [k | r] row stride

typedef __bf16 bf16x8 __attribute__((ext_vector_type(8)));
typedef float  f32x4  __attribute__((ext_vector_type(4)));

__device__ __forceinline__ ushort f2bf(float x) { __bf16 b = (__bf16)x; return __builtin_bit_cast(ushort, b); }
__device__ __forceinline__ float  bf2f(ushort u) { unsigned v = ((unsigned)u) << 16; return __builtin_bit_cast(float, v); }

__device__ __forceinline__ float4 f4z() { return make_float4(0.f, 0.f, 0.f, 0.f); }
__device__ __forceinline__ float4 ld4p(const float* p, bool v) { return v ? *(const float4*)p : f4z(); }
__device__ __forceinline__ float4 add4(float4 a, float4 b) {
    return make_float4(a.x + b.x, a.y + b.y, a.z + b.z, a.w + b.w);
}
__device__ __forceinline__ uint4 pack8(float4 a, float4 b) {
    ushort u[8] = { f2bf(a.x), f2bf(a.y), f2bf(a.z), f2bf(a.w),
                    f2bf(b.x), f2bf(b.y), f2bf(b.z), f2bf(b.w) };
    return *(uint4*)u;
}

// ---------------- double-buffered 128x64 MFMA GEMM core (staging via functor) ----
template<class F>
__device__ __forceinline__ void gemm_core(
    F&& ld, const float* __restrict__ bias,
    void* __restrict__ Cv, int ldc, int outbf,
    int m0, int n0, int kFrom, int kTo,
    ushort (*As)[128][40], ushort (*Bs)[64][40])
{
    const int tid = threadIdx.x, lane = tid & 63, wave = tid >> 6;
    const int wm = (wave >> 1) * 64, wn = (wave & 1) * 32;
    const int sr = tid >> 2, sc = (tid & 3) * 8;

    f32x4 acc[4][2] = {};

    auto compute = [&](int b) {
        const int ko = (lane >> 4) * 8;
        bf16x8 af[4], bfr[2];
#pragma unroll
        for (int i = 0; i < 4; i++)
            af[i] = __builtin_bit_cast(bf16x8, *(const uint4*)&As[b][wm + i * 16 + (lane & 15)][ko]);
#pragma unroll
        for (int j = 0; j < 2; j++)
            bfr[j] = __builtin_bit_cast(bf16x8, *(const uint4*)&Bs[b][wn + j * 16 + (lane & 15)][ko]);
#pragma unroll
        for (int i = 0; i < 4; i++)
#pragma unroll
            for (int j = 0; j < 2; j++)
                acc[i][j] = __builtin_amdgcn_mfma_f32_16x16x32_bf16(af[i], bfr[j], acc[i][j], 0, 0, 0);
    };

    uint4 a0, a1, b0;
    ld(kFrom, a0, a1, b0);
    *(uint4*)&As[0][sr][sc] = a0;
    *(uint4*)&As[0][sr + 64][sc] = a1;
    *(uint4*)&Bs[0][sr][sc] = b0;
    __syncthreads();

    int cur = 0;
    for (int k0 = kFrom + 32; k0 < kTo; k0 += 32) {
        ld(k0, a0, a1, b0);
        compute(cur);
        *(uint4*)&As[cur ^ 1][sr][sc] = a0;
        *(uint4*)&As[cur ^ 1][sr + 64][sc] = a1;
        *(uint4*)&Bs[cur ^ 1][sr][sc] = b0;
        __syncthreads();
        cur ^= 1;
    }
    compute(cur);

    float* Cf = (float*)Cv;
    ushort* Cb = (ushort*)Cv;
#pragma unroll
    for (int i = 0; i < 4; i++) {
#pragma unroll
        for (int j = 0; j < 2; j++) {
            int row = m0 + wm + i * 16 + (lane >> 4) * 4;
            int col = n0 + wn + j * 16 + (lane & 15);
#pragma unroll
            for (int r = 0; r < 4; r++) {
                float val = acc[i][j][r];
                if (bias) val += bias[col];
                if (outbf) Cb[(size_t)(row + r) * ldc + col] = f2bf(val);
                else       Cf[(size_t)(row + r) * ldc + col] = val;
            }
        }
    }
}

// ---------------- k1: z=0 k-GEMM, z=1 v-GEMM (inline f32->bf16), z>=2 Wcat repack ----
__global__ __launch_bounds__(256) void k1_kernel(
    const float* __restrict__ x,
    const float* __restrict__ ke_w, const float* __restrict__ ke_b, ushort* __restrict__ kr,
    const float* __restrict__ ve_w, const float* __restrict__ ve_b, float* __restrict__ v,
    const float* __restrict__ er_w, const float* __restrict__ er_b,
    const float* __restrict__ ad_w, const float* __restrict__ ad_b,
    ushort* __restrict__ wcat)
{
    __shared__ ushort As[2][128][40];
    __shared__ ushort Bs[2][64][40];
    const int z = blockIdx.z;
    const int sr = threadIdx.x >> 2, sc = (threadIdx.x & 3) * 8;

    if (z == 0) {
        const int m0 = blockIdx.y * 128, n0 = blockIdx.x * 64;
        auto ld = [&](int k0, uint4& A0, uint4& A1, uint4& B0) {
            int c0 = k0 + sc, c4 = c0 + 4;
            bool v0 = c0 < C_, v4 = c4 < C_;
            const float* r0 = x + (size_t)(m0 + sr) * IN_;
            const float* r1 = x + (size_t)(m0 + sr + 64) * IN_;
            A0 = pack8(add4(ld4p(r0 + c0, v0), ld4p(r0 + C_ + c0, v0)),
                       add4(ld4p(r0 + c4, v4), ld4p(r0 + C_ + c4, v4)));
            A1 = pack8(add4(ld4p(r1 + c0, v0), ld4p(r1 + C_ + c0, v0)),
                       add4(ld4p(r1 + c4, v4), ld4p(r1 + C_ + c4, v4)));
            const float* rb = ke_w + (size_t)(n0 + sr) * C_;
            B0 = pack8(ld4p(rb + c0, v0), ld4p(rb + c4, v4));
        };
        gemm_core(ld, ke_b, kr, KS, 1, m0, n0, 0, KQ, As, Bs);
    } else if (z == 1) {
        const int m0 = blockIdx.y * 128, n0 = blockIdx.x * 64;
        auto ld = [&](int k0, uint4& A0, uint4& A1, uint4& B0) {
            int c0 = k0 + sc, c4 = c0 + 4;
            bool v0 = c0 < IN_, v4 = c4 < IN_;
            const float* r0 = x + (size_t)(m0 + sr) * IN_;
            const float* r1 = x + (size_t)(m0 + sr + 64) * IN_;
            A0 = pack8(ld4p(r0 + c0, v0), ld4p(r0 + c4, v4));
            A1 = pack8(ld4p(r1 + c0, v0), ld4p(r1 + c4, v4));
            const float* rb = ve_w + (size_t)(n0 + sr) * IN_;
            B0 = pack8(ld4p(rb + c0, v0), ld4p(rb + c4, v4));
        };
        gemm_core(ld, ve_b, v, H_, 0, m0, n0, 0, KX, As, Bs);
    } else {
        int idx = ((z - 2) * 64 + blockIdx.y * 4 + blockIdx.x) * 256 + threadIdx.x;
        if (idx >= 512 * (KBIG / 4)) return;
        int oc = idx / (KBIG / 4), g = idx % (KBIG / 4), c0 = g * 4;
        const float* Wsrc = (oc < 256) ? er_w : ad_w;
        const float* bsrc = (oc < 256) ? er_b : ad_b;
        int oo = oc & 255;
        ushort pk[4];
#pragma unroll
        for (int j = 0; j < 4; j++) {
            int c = c0 + j;
            float val = 0.f;
            if (c < 2048)      { int d = c >> 8, ii = c & 255; val = Wsrc[(size_t)(d * 256 + oo) * 256 + ii]; }
            else if (c < 2056) { val = bsrc[(c - 2048) * 256 + oo]; }
            pk[j] = f2bf(val);
        }
        *(ushort4*)&wcat[(size_t)oc * KBIG + c0] = *(ushort4*)pk;
    }
}

// ---------------- vww: b<32 -> wlog GEMM (km_w inline cvt); else vw fill for n=b-32 ----
__global__ __launch_bounds__(256) void vww_kernel(
    const ushort* __restrict__ kr, const float* __restrict__ v,
    const float* __restrict__ kw2_w, const float* __restrict__ kw2_b,
    const float* __restrict__ km_w, const float* __restrict__ km_b,
    float* __restrict__ wlog, ushort* __restrict__ vw)
{
    __shared__ ushort As[2][128][40];
    __shared__ ushort Bs[2][64][40];
    __shared__ float kf[H_], vl[H_], lg[8], w2l[8];
    const int b = blockIdx.x, t = threadIdx.x;
    const int sr = t >> 2, sc = (t & 3) * 8;

    if (b < 32) {
        const int m0 = (b >> 1) * 128, n0 = (b & 1) * 64;
        auto ld = [&](int k0, uint4& A0, uint4& A1, uint4& B0) {
            A0 = *(const uint4*)&kr[(size_t)(m0 + sr) * KS + k0 + sc];
            A1 = *(const uint4*)&kr[(size_t)(m0 + sr + 64) * KS + k0 + sc];
            int c0 = k0 + sc, c4 = c0 + 4;
            const float* rb = km_w + (size_t)(n0 + sr) * H_;
            B0 = pack8(*(const float4*)(rb + c0), *(const float4*)(rb + c4));
        };
        gemm_core(ld, km_b, wlog, M_, 0, m0, n0, 0, H_, As, Bs);
        return;
    }

    const int n = b - 32;
    if (t < 64) {
        ushort4 u = ((const ushort4*)(kr + (size_t)n * KS))[t];
        kf[t * 4 + 0] = bf2f(u.x); kf[t * 4 + 1] = bf2f(u.y);
        kf[t * 4 + 2] = bf2f(u.z); kf[t * 4 + 3] = bf2f(u.w);
        float4 vv = ((const float4*)(v + (size_t)n * H_))[t];
        vl[t * 4 + 0] = vv.x; vl[t * 4 + 1] = vv.y;
        vl[t * 4 + 2] = vv.z; vl[t * 4 + 3] = vv.w;
    }
    __syncthreads();
    {
        int d = t >> 5, l = t & 31;
        float acc = 0.f;
        const float* wr = kw2_w + d * H_;
#pragma unroll
        for (int s = 0; s < 8; s++) acc += kf[l + 32 * s] * wr[l + 32 * s];
#pragma unroll
        for (int off = 16; off; off >>= 1) acc += __shfl_xor(acc, off);
        if (l == 0) lg[d] = acc + kw2_b[d];
    }
    __syncthreads();
    if (t < 8) {
        float val = lg[t];
        float mx = val;
#pragma unroll
        for (int off = 1; off < 8; off <<= 1) mx = fmaxf(mx, __shfl_xor(mx, off));
        float e = expf(val - mx), s = e;
#pragma unroll
        for (int off = 1; off < 8; off <<= 1) s += __shfl_xor(s, off);
        w2l[t] = e / s;
    }
    __syncthreads();
    ushort* row = vw + (size_t)n * KBIG;
    for (int g = t; g < KBIG / 4; g += 256) {
        int c0 = g * 4;
        ushort pk[4];
#pragma unroll
        for (int j = 0; j < 4; j++) {
            int c = c0 + j;
            float val = 0.f;
            if (c < 2048)      val = w2l[c >> 8] * vl[c & 255];
            else if (c < 2056) val = w2l[c - 2048];
            pk[j] = f2bf(val);
        }
        *(ushort4*)&row[c0] = *(ushort4*)pk;
    }
}

// ---------------- bigw: big expert GEMM, K split x NZ ----------------
__global__ __launch_bounds__(256) void bigw_kernel(
    const ushort* __restrict__ vw, const ushort* __restrict__ Wcat,
    float* __restrict__ parts)
{
    __shared__ ushort As[2][128][40];
    __shared__ ushort Bs[2][64][40];
    const int z = blockIdx.z;
    const int m0 = blockIdx.y * 128, n0 = blockIdx.x * 64;
    const int sr = threadIdx.x >> 2, sc = (threadIdx.x & 3) * 8;
    auto ld = [&](int k0, uint4& A0, uint4& A1, uint4& B0) {
        A0 = *(const uint4*)&vw[(size_t)(m0 + sr) * KBIG + k0 + sc];
        A1 = *(const uint4*)&vw[(size_t)(m0 + sr + 64) * KBIG + k0 + sc];
        B0 = *(const uint4*)&Wcat[(size_t)(n0 + sr) * KBIG + k0 + sc];
    };
    gemm_core(ld, nullptr, parts + (size_t)z * N_ * 512, 512, 0,
              m0, n0, z * KSPL, (z + 1) * KSPL, As, Bs);
}

// ---------------- streaming memory pass (NT loads + NT stores, R6-measured-best) ----
// block = (n, half): softmax(wlog[n]) -> wl; e/a from parts (own 128 h's);
// stream 128 rows: r-reduce -> kr[:,256+h] bf16 ; erase/add -> mem_out
__global__ __launch_bounds__(256) void mem_stream_kernel(
    const float* __restrict__ mem_in,
    const float* __restrict__ wlog,        // N x 128 logits
    const float* __restrict__ parts,       // NZ x N x 512
    float* __restrict__ mem_out,
    ushort* __restrict__ kr)
{
    __shared__ float wl[M_];
    __shared__ float el[128], al[128];
    __shared__ float red[4];
    const int n = blockIdx.x >> 1, half = blockIdx.x & 1, hbase = half * 128;
    const int t = threadIdx.x;

    const int col = (t < 128) ? (hbase + t) : (256 + hbase + (t - 128));
    float pacc = 0.f;
#pragma unroll
    for (int z = 0; z < NZ; z++)
        pacc += parts[(size_t)z * N_ * 512 + (size_t)n * 512 + col];

    float lv = 0.f;
    if (t < 128) {
        lv = wlog[(size_t)n * M_ + t];
        float mx = lv;
#pragma unroll
        for (int off = 32; off; off >>= 1) mx = fmaxf(mx, __shfl_xor(mx, off));
        if ((t & 63) == 0) red[t >> 6] = mx;
        el[t] = 1.f / (1.f + expf(-pacc));
    } else {
        al[t - 128] = tanhf(pacc);
    }
    __syncthreads();
    if (t < 128) {
        float gmax = fmaxf(red[0], red[1]);
        float ev = expf(lv - gmax);
        float s = ev;
#pragma unroll
        for (int off = 32; off; off >>= 1) s += __shfl_xor(s, off);
        if ((t & 63) == 0) red[2 + (t >> 6)] = s;
        wl[t] = ev;
    }
    __syncthreads();
    if (t < 128) wl[t] *= 1.f / (red[2] + red[3]);
    __syncthreads();

    const int wave = t >> 6, lane = t & 63, half2 = lane >> 5, l32 = lane & 31;
    const f32x4* min4 = (const f32x4*)(mem_in + ((size_t)n * H_ + hbase) * M_);
    f32x4* mout4 = (f32x4*)(mem_out + ((size_t)n * H_ + hbase) * M_);
    f32x4 wv = ((const f32x4*)wl)[l32];
#pragma unroll 4
    for (int i = 0; i < 16; i++) {
        int hl = i * 8 + wave * 2 + half2;   // 0..127
        f32x4 mv = __builtin_nontemporal_load(&min4[hl * 32 + l32]);
        float eh = el[hl], ah = al[hl];
        f32x4 nv = mv * (1.f - wv * eh) + wv * ah;
        __builtin_nontemporal_store(nv, &mout4[hl * 32 + l32]);
        float racc = mv[0] * wv[0] + mv[1] * wv[1] + mv[2] * wv[2] + mv[3] * wv[3];
#pragma unroll
        for (int off = 1; off < 32; off <<= 1) racc += __shfl_xor(racc, off);
        if (l32 == 0) kr[(size_t)n * KS + H_ + hbase + hl] = f2bf(racc);
    }
}

// ---------------- fy: f = tanh(kr @ sum_w.T + sum_b) fused into y ----------------
__global__ __launch_bounds__(256) void fy_kernel(
    const ushort* __restrict__ kr, const float* __restrict__ sum_w,
    const float* __restrict__ sum_b, const float* __restrict__ out_w,
    const float* __restrict__ out_b, float* __restrict__ y)
{
    __shared__ ushort As[2][64][40];
    __shared__ ushort Bs[2][256][40];
    __shared__ float yl[64][4];
    const int tid = threadIdx.x, lane = tid & 63, wave = tid >> 6;
    const int wn = wave * 64;
    const int m0 = blockIdx.x * 64;
    const int sr = tid >> 2, sc = (tid & 3) * 8;

    f32x4 acc[4][4] = {};

    auto compute = [&](int b) {
        const int ko = (lane >> 4) * 8;
        bf16x8 af[4], bfr[4];
#pragma unroll
        for (int i = 0; i < 4; i++)
            af[i] = __builtin_bit_cast(bf16x8, *(const uint4*)&As[b][i * 16 + (lane & 15)][ko]);
#pragma unroll
        for (int j = 0; j < 4; j++)
            bfr[j] = __builtin_bit_cast(bf16x8, *(const uint4*)&Bs[b][wn + j * 16 + (lane & 15)][ko]);
#pragma unroll
        for (int i = 0; i < 4; i++)
#pragma unroll
            for (int j = 0; j < 4; j++)
                acc[i][j] = __builtin_amdgcn_mfma_f32_16x16x32_bf16(af[i], bfr[j], acc[i][j], 0, 0, 0);
    };

    auto stage = [&](int buf, int k0) {
        int c0 = k0 + sc, c4 = c0 + 4;
        *(uint4*)&As[buf][sr][sc] = *(const uint4*)&kr[(size_t)(m0 + sr) * KS + k0 + sc];
#pragma unroll
        for (int g = 0; g < 4; g++) {
            const float* rb = sum_w + (size_t)(sr + g * 64) * KS;
            *(uint4*)&Bs[buf][sr + g * 64][sc] = pack8(*(const float4*)(rb + c0), *(const float4*)(rb + c4));
        }
    };

    stage(0, 0);
    __syncthreads();
    int cur = 0;
    for (int k0 = 32; k0 < KS; k0 += 32) {
        compute(cur);
        stage(cur ^ 1, k0);
        __syncthreads();
        cur ^= 1;
    }
    compute(cur);

    float ow[4], sb[4];
#pragma unroll
    for (int j = 0; j < 4; j++) {
        int col = wn + j * 16 + (lane & 15);
        ow[j] = out_w[col];
        sb[j] = sum_b[col];
    }
    float yp[4][4];
#pragma unroll
    for (int i = 0; i < 4; i++)
#pragma unroll
        for (int r = 0; r < 4; r++) {
            float s = 0.f;
#pragma unroll
            for (int j = 0; j < 4; j++)
                s += tanhf(acc[i][j][r] + sb[j]) * ow[j];
            yp[i][r] = s;
        }
#pragma unroll
    for (int off = 1; off < 16; off <<= 1)
#pragma unroll
        for (int i = 0; i < 4; i++)
#pragma unroll
            for (int r = 0; r < 4; r++)
                yp[i][r] += __shfl_xor(yp[i][r], off);
    if ((lane & 15) == 0) {
#pragma unroll
        for (int i = 0; i < 4; i++)
#pragma unroll
            for (int r = 0; r < 4; r++)
                yl[i * 16 + (lane >> 4) * 4 + r][wave] = yp[i][r];
    }
    __syncthreads();
    if (tid < 64)
        y[m0 + tid] = yl[tid][0] + yl[tid][1] + yl[tid][2] + yl[tid][3] + out_b[0];
}

extern "C" void kernel_launch(void* const* d_in, const int* in_sizes, int n_in,
                              void* d_out, int out_size, void* d_ws, size_t ws_size,
                              hipStream_t stream) {
    const float* x      = (const float*)d_in[0];
    const float* mem_in = (const float*)d_in[1];
    const float* ke_w   = (const float*)d_in[2];
    const float* ke_b   = (const float*)d_in[3];
    const float* km_w   = (const float*)d_in[4];
    const float* km_b   = (const float*)d_in[5];
    const float* kw2_w  = (const float*)d_in[6];
    const float* kw2_b  = (const float*)d_in[7];
    const float* sum_w  = (const float*)d_in[8];
    const float* sum_b  = (const float*)d_in[9];
    const float* out_w  = (const float*)d_in[10];
    const float* out_b  = (const float*)d_in[11];
    const float* ve_w   = (const float*)d_in[12];
    const float* ve_b   = (const float*)d_in[13];
    const float* er_w   = (const float*)d_in[14];
    const float* er_b   = (const float*)d_in[15];
    const float* ad_w   = (const float*)d_in[16];
    const float* ad_b   = (const float*)d_in[17];

    float* y_out   = (float*)d_out;
    float* mem_out = (float*)d_out + N_;

    // ---- workspace (float units, 16B-aligned offsets), ~41 MB ----
    float* ws = (float*)d_ws;
    size_t o = 0;
    float*  parts = ws + o;            o += (size_t)NZ * N_ * 512;      // 6,291,456
    ushort* vw    = (ushort*)(ws + o); o += (size_t)N_ * KBIG / 2;      // 2,162,688
    ushort* Wcat  = (ushort*)(ws + o); o += (size_t)512 * KBIG / 2;     //   540,672
    ushort* kr    = (ushort*)(ws + o); o += (size_t)N_ * KS / 2;        //   524,288
    float*  v     = ws + o;            o += (size_t)N_ * H_;            //   524,288
    float*  wlog  = ws + o;            o += (size_t)N_ * M_;            //   262,144

    // 1. k-GEMM (z=0) + v-GEMM (z=1) + Wcat repack (z=2..18), inline f32->bf16
    k1_kernel<<<dim3(4, 16, 19), 256, 0, stream>>>(
        x, ke_w, ke_b, kr, ve_w, ve_b, v, er_w, er_b, ad_w, ad_b, Wcat);
    // 2. wlog GEMM (b<32) + w2/vw fill (b>=32)
    vww_kernel<<<32 + N_, 256, 0, stream>>>(
        kr, v, kw2_w, kw2_b, km_w, km_b, wlog, vw);
    // 3. big expert GEMM, K split x6 -> 768 blocks
    bigw_kernel<<<dim3(8, 16, NZ), 256, 0, stream>>>(vw, Wcat, parts);
    // 4. streaming memory pass (NT ld/st, inline softmax + e/a prologue)
    mem_stream_kernel<<<2 * N_, 256, 0, stream>>>(mem_in, wlog, parts, mem_out, kr);
    // 5. f GEMM fused with y reduction
    fy_kernel<<<N_ / 64, 256, 0, stream>>>(kr, sum_w, sum_b, out_w, out_b, y_out);
}

// Round 13
// 175.286 us; speedup vs baseline: 1.0982x; 1.0243x over previous
//
#include <hip/hip_runtime.h>
#include <math.h>

#define N_  2048
#define IN_ 400
#define C_  200
#define H_  256
#define M_  128
#define D_  8

#define KQ   224    // C_=200 padded to x32
#define KX   416    // IN_=400 padded to x32
#define KBIG 2112   // 2048 data + 8 bias + 56 pad (= 6*352, K-splittable x6)
#define NZ   6      // K-split of big GEMM
#define KSPL (KBIG / NZ)   // 352 = 11*32
#define KS   512    // [k | r] row stride

typedef __bf16 bf16x8 __attribute__((ext_vector_type(8)));
typedef float  f32x4  __attribute__((ext_vector_type(4)));

__device__ __forceinline__ ushort f2bf(float x) { __bf16 b = (__bf16)x; return __builtin_bit_cast(ushort, b); }
__device__ __forceinline__ float  bf2f(ushort u) { unsigned v = ((unsigned)u) << 16; return __builtin_bit_cast(float, v); }

__device__ __forceinline__ float4 f4z() { return make_float4(0.f, 0.f, 0.f, 0.f); }
__device__ __forceinline__ float4 ld4p(const float* p, bool v) { return v ? *(const float4*)p : f4z(); }
__device__ __forceinline__ float4 add4(float4 a, float4 b) {
    return make_float4(a.x + b.x, a.y + b.y, a.z + b.z, a.w + b.w);
}
__device__ __forceinline__ uint4 pack8(float4 a, float4 b) {
    ushort u[8] = { f2bf(a.x), f2bf(a.y), f2bf(a.z), f2bf(a.w),
                    f2bf(b.x), f2bf(b.y), f2bf(b.z), f2bf(b.w) };
    return *(uint4*)u;
}

// ---------------- double-buffered 128x64 MFMA GEMM core (staging via functor) ----
template<class F>
__device__ __forceinline__ void gemm_core(
    F&& ld, const float* __restrict__ bias,
    void* __restrict__ Cv, int ldc, int outbf,
    int m0, int n0, int kFrom, int kTo,
    ushort (*As)[128][40], ushort (*Bs)[64][40])
{
    const int tid = threadIdx.x, lane = tid & 63, wave = tid >> 6;
    const int wm = (wave >> 1) * 64, wn = (wave & 1) * 32;
    const int sr = tid >> 2, sc = (tid & 3) * 8;

    f32x4 acc[4][2] = {};

    auto compute = [&](int b) {
        const int ko = (lane >> 4) * 8;
        bf16x8 af[4], bfr[2];
#pragma unroll
        for (int i = 0; i < 4; i++)
            af[i] = __builtin_bit_cast(bf16x8, *(const uint4*)&As[b][wm + i * 16 + (lane & 15)][ko]);
#pragma unroll
        for (int j = 0; j < 2; j++)
            bfr[j] = __builtin_bit_cast(bf16x8, *(const uint4*)&Bs[b][wn + j * 16 + (lane & 15)][ko]);
#pragma unroll
        for (int i = 0; i < 4; i++)
#pragma unroll
            for (int j = 0; j < 2; j++)
                acc[i][j] = __builtin_amdgcn_mfma_f32_16x16x32_bf16(af[i], bfr[j], acc[i][j], 0, 0, 0);
    };

    uint4 a0, a1, b0;
    ld(kFrom, a0, a1, b0);
    *(uint4*)&As[0][sr][sc] = a0;
    *(uint4*)&As[0][sr + 64][sc] = a1;
    *(uint4*)&Bs[0][sr][sc] = b0;
    __syncthreads();

    int cur = 0;
    for (int k0 = kFrom + 32; k0 < kTo; k0 += 32) {
        ld(k0, a0, a1, b0);
        compute(cur);
        *(uint4*)&As[cur ^ 1][sr][sc] = a0;
        *(uint4*)&As[cur ^ 1][sr + 64][sc] = a1;
        *(uint4*)&Bs[cur ^ 1][sr][sc] = b0;
        __syncthreads();
        cur ^= 1;
    }
    compute(cur);

    float* Cf = (float*)Cv;
    ushort* Cb = (ushort*)Cv;
#pragma unroll
    for (int i = 0; i < 4; i++) {
#pragma unroll
        for (int j = 0; j < 2; j++) {
            int row = m0 + wm + i * 16 + (lane >> 4) * 4;
            int col = n0 + wn + j * 16 + (lane & 15);
#pragma unroll
            for (int r = 0; r < 4; r++) {
                float val = acc[i][j][r];
                if (bias) val += bias[col];
                if (outbf) Cb[(size_t)(row + r) * ldc + col] = f2bf(val);
                else       Cf[(size_t)(row + r) * ldc + col] = val;
            }
        }
    }
}

// ---------------- k1: z=0 k-GEMM, z=1 v-GEMM (inline f32->bf16), z>=2 Wcat repack ----
__global__ __launch_bounds__(256) void k1_kernel(
    const float* __restrict__ x,
    const float* __restrict__ ke_w, const float* __restrict__ ke_b, ushort* __restrict__ kr,
    const float* __restrict__ ve_w, const float* __restrict__ ve_b, float* __restrict__ v,
    const float* __restrict__ er_w, const float* __restrict__ er_b,
    const float* __restrict__ ad_w, const float* __restrict__ ad_b,
    ushort* __restrict__ wcat)
{
    __shared__ ushort As[2][128][40];
    __shared__ ushort Bs[2][64][40];
    const int z = blockIdx.z;
    const int sr = threadIdx.x >> 2, sc = (threadIdx.x & 3) * 8;

    if (z == 0) {
        const int m0 = blockIdx.y * 128, n0 = blockIdx.x * 64;
        auto ld = [&](int k0, uint4& A0, uint4& A1, uint4& B0) {
            int c0 = k0 + sc, c4 = c0 + 4;
            bool v0 = c0 < C_, v4 = c4 < C_;
            const float* r0 = x + (size_t)(m0 + sr) * IN_;
            const float* r1 = x + (size_t)(m0 + sr + 64) * IN_;
            A0 = pack8(add4(ld4p(r0 + c0, v0), ld4p(r0 + C_ + c0, v0)),
                       add4(ld4p(r0 + c4, v4), ld4p(r0 + C_ + c4, v4)));
            A1 = pack8(add4(ld4p(r1 + c0, v0), ld4p(r1 + C_ + c0, v0)),
                       add4(ld4p(r1 + c4, v4), ld4p(r1 + C_ + c4, v4)));
            const float* rb = ke_w + (size_t)(n0 + sr) * C_;
            B0 = pack8(ld4p(rb + c0, v0), ld4p(rb + c4, v4));
        };
        gemm_core(ld, ke_b, kr, KS, 1, m0, n0, 0, KQ, As, Bs);
    } else if (z == 1) {
        const int m0 = blockIdx.y * 128, n0 = blockIdx.x * 64;
        auto ld = [&](int k0, uint4& A0, uint4& A1, uint4& B0) {
            int c0 = k0 + sc, c4 = c0 + 4;
            bool v0 = c0 < IN_, v4 = c4 < IN_;
            const float* r0 = x + (size_t)(m0 + sr) * IN_;
            const float* r1 = x + (size_t)(m0 + sr + 64) * IN_;
            A0 = pack8(ld4p(r0 + c0, v0), ld4p(r0 + c4, v4));
            A1 = pack8(ld4p(r1 + c0, v0), ld4p(r1 + c4, v4));
            const float* rb = ve_w + (size_t)(n0 + sr) * IN_;
            B0 = pack8(ld4p(rb + c0, v0), ld4p(rb + c4, v4));
        };
        gemm_core(ld, ve_b, v, H_, 0, m0, n0, 0, KX, As, Bs);
    } else {
        int idx = ((z - 2) * 64 + blockIdx.y * 4 + blockIdx.x) * 256 + threadIdx.x;
        if (idx >= 512 * (KBIG / 4)) return;
        int oc = idx / (KBIG / 4), g = idx % (KBIG / 4), c0 = g * 4;
        const float* Wsrc = (oc < 256) ? er_w : ad_w;
        const float* bsrc = (oc < 256) ? er_b : ad_b;
        int oo = oc & 255;
        ushort pk[4];
#pragma unroll
        for (int j = 0; j < 4; j++) {
            int c = c0 + j;
            float val = 0.f;
            if (c < 2048)      { int d = c >> 8, ii = c & 255; val = Wsrc[(size_t)(d * 256 + oo) * 256 + ii]; }
            else if (c < 2056) { val = bsrc[(c - 2048) * 256 + oo]; }
            pk[j] = f2bf(val);
        }
        *(ushort4*)&wcat[(size_t)oc * KBIG + c0] = *(ushort4*)pk;
    }
}

// ---------------- vww: b<32 -> wlog GEMM (km_w inline cvt); else vw fill for n=b-32 ----
__global__ __launch_bounds__(256) void vww_kernel(
    const ushort* __restrict__ kr, const float* __restrict__ v,
    const float* __restrict__ kw2_w, const float* __restrict__ kw2_b,
    const float* __restrict__ km_w, const float* __restrict__ km_b,
    float* __restrict__ wlog, ushort* __restrict__ vw)
{
    __shared__ ushort As[2][128][40];
    __shared__ ushort Bs[2][64][40];
    __shared__ float kf[H_], vl[H_], lg[8], w2l[8];
    const int b = blockIdx.x, t = threadIdx.x;
    const int sr = t >> 2, sc = (t & 3) * 8;

    if (b < 32) {
        const int m0 = (b >> 1) * 128, n0 = (b & 1) * 64;
        auto ld = [&](int k0, uint4& A0, uint4& A1, uint4& B0) {
            A0 = *(const uint4*)&kr[(size_t)(m0 + sr) * KS + k0 + sc];
            A1 = *(const uint4*)&kr[(size_t)(m0 + sr + 64) * KS + k0 + sc];
            int c0 = k0 + sc, c4 = c0 + 4;
            const float* rb = km_w + (size_t)(n0 + sr) * H_;
            B0 = pack8(*(const float4*)(rb + c0), *(const float4*)(rb + c4));
        };
        gemm_core(ld, km_b, wlog, M_, 0, m0, n0, 0, H_, As, Bs);
        return;
    }

    const int n = b - 32;
    if (t < 64) {
        ushort4 u = ((const ushort4*)(kr + (size_t)n * KS))[t];
        kf[t * 4 + 0] = bf2f(u.x); kf[t * 4 + 1] = bf2f(u.y);
        kf[t * 4 + 2] = bf2f(u.z); kf[t * 4 + 3] = bf2f(u.w);
        float4 vv = ((const float4*)(v + (size_t)n * H_))[t];
        vl[t * 4 + 0] = vv.x; vl[t * 4 + 1] = vv.y;
        vl[t * 4 + 2] = vv.z; vl[t * 4 + 3] = vv.w;
    }
    __syncthreads();
    {
        int d = t >> 5, l = t & 31;
        float acc = 0.f;
        const float* wr = kw2_w + d * H_;
#pragma unroll
        for (int s = 0; s < 8; s++) acc += kf[l + 32 * s] * wr[l + 32 * s];
#pragma unroll
        for (int off = 16; off; off >>= 1) acc += __shfl_xor(acc, off);
        if (l == 0) lg[d] = acc + kw2_b[d];
    }
    __syncthreads();
    if (t < 8) {
        float val = lg[t];
        float mx = val;
#pragma unroll
        for (int off = 1; off < 8; off <<= 1) mx = fmaxf(mx, __shfl_xor(mx, off));
        float e = expf(val - mx), s = e;
#pragma unroll
        for (int off = 1; off < 8; off <<= 1) s += __shfl_xor(s, off);
        w2l[t] = e / s;
    }
    __syncthreads();
    ushort* row = vw + (size_t)n * KBIG;
    for (int g = t; g < KBIG / 4; g += 256) {
        int c0 = g * 4;
        ushort pk[4];
#pragma unroll
        for (int j = 0; j < 4; j++) {
            int c = c0 + j;
            float val = 0.f;
            if (c < 2048)      val = w2l[c >> 8] * vl[c & 255];
            else if (c < 2056) val = w2l[c - 2048];
            pk[j] = f2bf(val);
        }
        *(ushort4*)&row[c0] = *(ushort4*)pk;
    }
}

// ---------------- bigw: big expert GEMM, K split x NZ ----------------
__global__ __launch_bounds__(256) void bigw_kernel(
    const ushort* __restrict__ vw, const ushort* __restrict__ Wcat,
    float* __restrict__ parts)
{
    __shared__ ushort As[2][128][40];
    __shared__ ushort Bs[2][64][40];
    const int z = blockIdx.z;
    const int m0 = blockIdx.y * 128, n0 = blockIdx.x * 64;
    const int sr = threadIdx.x >> 2, sc = (threadIdx.x & 3) * 8;
    auto ld = [&](int k0, uint4& A0, uint4& A1, uint4& B0) {
        A0 = *(const uint4*)&vw[(size_t)(m0 + sr) * KBIG + k0 + sc];
        A1 = *(const uint4*)&vw[(size_t)(m0 + sr + 64) * KBIG + k0 + sc];
        B0 = *(const uint4*)&Wcat[(size_t)(n0 + sr) * KBIG + k0 + sc];
    };
    gemm_core(ld, nullptr, parts + (size_t)z * N_ * 512, 512, 0,
              m0, n0, z * KSPL, (z + 1) * KSPL, As, Bs);
}

// ---------------- streaming memory pass: NO cross-lane ops in the hot loop ----------
// block = (n, half): softmax(wlog[n]) -> wl; e/a from parts; stream 128 rows with
// per-lane dot-partials written to LDS (fire-and-forget ds_write); one barrier;
// 128-thread LDS reduction -> coalesced kr stores. LN-structure (82% BW ref).
__global__ __launch_bounds__(256) void mem_stream_kernel(
    const float* __restrict__ mem_in,
    const float* __restrict__ wlog,        // N x 128 logits
    const float* __restrict__ parts,       // NZ x N x 512
    float* __restrict__ mem_out,
    ushort* __restrict__ kr)
{
    __shared__ float wl[M_];
    __shared__ float el[128], al[128];
    __shared__ float red[4];
    __shared__ float part[128][33];        // [row][lane-partial], +1 pad
    const int n = blockIdx.x >> 1, half = blockIdx.x & 1, hbase = half * 128;
    const int t = threadIdx.x;

    const int col = (t < 128) ? (hbase + t) : (256 + hbase + (t - 128));
    float pacc = 0.f;
#pragma unroll
    for (int z = 0; z < NZ; z++)
        pacc += parts[(size_t)z * N_ * 512 + (size_t)n * 512 + col];

    float lv = 0.f;
    if (t < 128) {
        lv = wlog[(size_t)n * M_ + t];
        float mx = lv;
#pragma unroll
        for (int off = 32; off; off >>= 1) mx = fmaxf(mx, __shfl_xor(mx, off));
        if ((t & 63) == 0) red[t >> 6] = mx;
        el[t] = 1.f / (1.f + expf(-pacc));
    } else {
        al[t - 128] = tanhf(pacc);
    }
    __syncthreads();
    if (t < 128) {
        float gmax = fmaxf(red[0], red[1]);
        float ev = expf(lv - gmax);
        float s = ev;
#pragma unroll
        for (int off = 32; off; off >>= 1) s += __shfl_xor(s, off);
        if ((t & 63) == 0) red[2 + (t >> 6)] = s;
        wl[t] = ev;
    }
    __syncthreads();
    if (t < 128) wl[t] *= 1.f / (red[2] + red[3]);
    __syncthreads();

    const int wave = t >> 6, lane = t & 63, half2 = lane >> 5, l32 = lane & 31;
    const int hrow = wave * 2 + half2;     // 0..7
    const f32x4* min4 = (const f32x4*)(mem_in + ((size_t)n * H_ + hbase) * M_);
    f32x4* mout4 = (f32x4*)(mem_out + ((size_t)n * H_ + hbase) * M_);
    f32x4 wv = ((const f32x4*)wl)[l32];

    // hot loop: load / fma / store / ds_write — zero cross-lane, zero dependence chains
#pragma unroll 4
    for (int i = 0; i < 16; i++) {
        int hl = i * 8 + hrow;             // 0..127, unique per (i, lane-group)
        f32x4 mv = __builtin_nontemporal_load(&min4[hl * 32 + l32]);
        float eh = el[hl], ah = al[hl];
        f32x4 nv = mv * (1.f - wv * eh) + wv * ah;
        __builtin_nontemporal_store(nv, &mout4[hl * 32 + l32]);
        part[hl][l32] = mv[0] * wv[0] + mv[1] * wv[1] + mv[2] * wv[2] + mv[3] * wv[3];
    }
    __syncthreads();

    // epilogue: 128 threads each reduce one row's 32 partials; coalesced kr stores
    if (t < 128) {
        float r = 0.f;
#pragma unroll
        for (int j = 0; j < 32; j++) r += part[t][j];
        kr[(size_t)n * KS + H_ + hbase + t] = f2bf(r);
    }
}

// ---------------- fy: f = tanh(kr @ sum_w.T + sum_b) fused into y ----------------
__global__ __launch_bounds__(256) void fy_kernel(
    const ushort* __restrict__ kr, const float* __restrict__ sum_w,
    const float* __restrict__ sum_b, const float* __restrict__ out_w,
    const float* __restrict__ out_b, float* __restrict__ y)
{
    __shared__ ushort As[2][64][40];
    __shared__ ushort Bs[2][256][40];
    __shared__ float yl[64][4];
    const int tid = threadIdx.x, lane = tid & 63, wave = tid >> 6;
    const int wn = wave * 64;
    const int m0 = blockIdx.x * 64;
    const int sr = tid >> 2, sc = (tid & 3) * 8;

    f32x4 acc[4][4] = {};

    auto compute = [&](int b) {
        const int ko = (lane >> 4) * 8;
        bf16x8 af[4], bfr[4];
#pragma unroll
        for (int i = 0; i < 4; i++)
            af[i] = __builtin_bit_cast(bf16x8, *(const uint4*)&As[b][i * 16 + (lane & 15)][ko]);
#pragma unroll
        for (int j = 0; j < 4; j++)
            bfr[j] = __builtin_bit_cast(bf16x8, *(const uint4*)&Bs[b][wn + j * 16 + (lane & 15)][ko]);
#pragma unroll
        for (int i = 0; i < 4; i++)
#pragma unroll
            for (int j = 0; j < 4; j++)
                acc[i][j] = __builtin_amdgcn_mfma_f32_16x16x32_bf16(af[i], bfr[j], acc[i][j], 0, 0, 0);
    };

    auto stage = [&](int buf, int k0) {
        int c0 = k0 + sc, c4 = c0 + 4;
        *(uint4*)&As[buf][sr][sc] = *(const uint4*)&kr[(size_t)(m0 + sr) * KS + k0 + sc];
#pragma unroll
        for (int g = 0; g < 4; g++) {
            const float* rb = sum_w + (size_t)(sr + g * 64) * KS;
            *(uint4*)&Bs[buf][sr + g * 64][sc] = pack8(*(const float4*)(rb + c0), *(const float4*)(rb + c4));
        }
    };

    stage(0, 0);
    __syncthreads();
    int cur = 0;
    for (int k0 = 32; k0 < KS; k0 += 32) {
        compute(cur);
        stage(cur ^ 1, k0);
        __syncthreads();
        cur ^= 1;
    }
    compute(cur);

    float ow[4], sb[4];
#pragma unroll
    for (int j = 0; j < 4; j++) {
        int col = wn + j * 16 + (lane & 15);
        ow[j] = out_w[col];
        sb[j] = sum_b[col];
    }
    float yp[4][4];
#pragma unroll
    for (int i = 0; i < 4; i++)
#pragma unroll
        for (int r = 0; r < 4; r++) {
            float s = 0.f;
#pragma unroll
            for (int j = 0; j < 4; j++)
                s += tanhf(acc[i][j][r] + sb[j]) * ow[j];
            yp[i][r] = s;
        }
#pragma unroll
    for (int off = 1; off < 16; off <<= 1)
#pragma unroll
        for (int i = 0; i < 4; i++)
#pragma unroll
            for (int r = 0; r < 4; r++)
                yp[i][r] += __shfl_xor(yp[i][r], off);
    if ((lane & 15) == 0) {
#pragma unroll
        for (int i = 0; i < 4; i++)
#pragma unroll
            for (int r = 0; r < 4; r++)
                yl[i * 16 + (lane >> 4) * 4 + r][wave] = yp[i][r];
    }
    __syncthreads();
    if (tid < 64)
        y[m0 + tid] = yl[tid][0] + yl[tid][1] + yl[tid][2] + yl[tid][3] + out_b[0];
}

extern "C" void kernel_launch(void* const* d_in, const int* in_sizes, int n_in,
                              void* d_out, int out_size, void* d_ws, size_t ws_size,
                              hipStream_t stream) {
    const float* x      = (const float*)d_in[0];
    const float* mem_in = (const float*)d_in[1];
    const float* ke_w   = (const float*)d_in[2];
    const float* ke_b   = (const float*)d_in[3];
    const float* km_w   = (const float*)d_in[4];
    const float* km_b   = (const float*)d_in[5];
    const float* kw2_w  = (const float*)d_in[6];
    const float* kw2_b  = (const float*)d_in[7];
    const float* sum_w  = (const float*)d_in[8];
    const float* sum_b  = (const float*)d_in[9];
    const float* out_w  = (const float*)d_in[10];
    const float* out_b  = (const float*)d_in[11];
    const float* ve_w   = (const float*)d_in[12];
    const float* ve_b   = (const float*)d_in[13];
    const float* er_w   = (const float*)d_in[14];
    const float* er_b   = (const float*)d_in[15];
    const float* ad_w   = (const float*)d_in[16];
    const float* ad_b   = (const float*)d_in[17];

    float* y_out   = (float*)d_out;
    float* mem_out = (float*)d_out + N_;

    // ---- workspace (float units, 16B-aligned offsets), ~41 MB ----
    float* ws = (float*)d_ws;
    size_t o = 0;
    float*  parts = ws + o;            o += (size_t)NZ * N_ * 512;      // 6,291,456
    ushort* vw    = (ushort*)(ws + o); o += (size_t)N_ * KBIG / 2;      // 2,162,688
    ushort* Wcat  = (ushort*)(ws + o); o += (size_t)512 * KBIG / 2;     //   540,672
    ushort* kr    = (ushort*)(ws + o); o += (size_t)N_ * KS / 2;        //   524,288
    float*  v     = ws + o;            o += (size_t)N_ * H_;            //   524,288
    float*  wlog  = ws + o;            o += (size_t)N_ * M_;            //   262,144

    // 1. k-GEMM (z=0) + v-GEMM (z=1) + Wcat repack (z=2..18), inline f32->bf16
    k1_kernel<<<dim3(4, 16, 19), 256, 0, stream>>>(
        x, ke_w, ke_b, kr, ve_w, ve_b, v, er_w, er_b, ad_w, ad_b, Wcat);
    // 2. wlog GEMM (b<32) + w2/vw fill (b>=32)
    vww_kernel<<<32 + N_, 256, 0, stream>>>(
        kr, v, kw2_w, kw2_b, km_w, km_b, wlog, vw);
    // 3. big expert GEMM, K split x6 -> 768 blocks
    bigw_kernel<<<dim3(8, 16, NZ), 256, 0, stream>>>(vw, Wcat, parts);
    // 4. streaming memory pass: zero cross-lane in hot loop, LDS partials
    mem_stream_kernel<<<2 * N_, 256, 0, stream>>>(mem_in, wlog, parts, mem_out, kr);
    // 5. f GEMM fused with y reduction
    fy_kernel<<<N_ / 64, 256, 0, stream>>>(kr, sum_w, sum_b, out_w, out_b, y_out);
}

// Round 14
// 167.382 us; speedup vs baseline: 1.1501x; 1.0472x over previous
//
#include <hip/hip_runtime.h>
#include <math.h>

#define N_  2048
#define IN_ 400
#define C_  200
#define H_  256
#define M_  128
#define D_  8

#define KQ   224    // C_=200 padded to x32
#define KX   416    // IN_=400 padded to x32
#define KBIG 2112   // 2048 data + 8 bias + 56 pad (= 6*352, K-splittable x6)
#define NZ   6      // K-split of big GEMM
#define KSPL (KBIG / NZ)   // 352 = 11*32
#define KS   512    // [k | r] row stride

typedef __bf16 bf16x8 __attribute__((ext_vector_type(8)));
typedef float  f32x4  __attribute__((ext_vector_type(4)));

typedef const __attribute__((address_space(1))) unsigned int* gas_t;
typedef __attribute__((address_space(3))) unsigned int* las_t;

__device__ __forceinline__ ushort f2bf(float x) { __bf16 b = (__bf16)x; return __builtin_bit_cast(ushort, b); }
__device__ __forceinline__ float  bf2f(ushort u) { unsigned v = ((unsigned)u) << 16; return __builtin_bit_cast(float, v); }

__device__ __forceinline__ float4 f4z() { return make_float4(0.f, 0.f, 0.f, 0.f); }
__device__ __forceinline__ float4 ld4p(const float* p, bool v) { return v ? *(const float4*)p : f4z(); }
__device__ __forceinline__ float4 add4(float4 a, float4 b) {
    return make_float4(a.x + b.x, a.y + b.y, a.z + b.z, a.w + b.w);
}
__device__ __forceinline__ uint4 pack8(float4 a, float4 b) {
    ushort u[8] = { f2bf(a.x), f2bf(a.y), f2bf(a.z), f2bf(a.w),
                    f2bf(b.x), f2bf(b.y), f2bf(b.z), f2bf(b.w) };
    return *(uint4*)u;
}

// ---------------- double-buffered 128x64 MFMA GEMM core (staging via functor) ----
template<class F>
__device__ __forceinline__ void gemm_core(
    F&& ld, const float* __restrict__ bias,
    void* __restrict__ Cv, int ldc, int outbf,
    int m0, int n0, int kFrom, int kTo,
    ushort (*As)[128][40], ushort (*Bs)[64][40])
{
    const int tid = threadIdx.x, lane = tid & 63, wave = tid >> 6;
    const int wm = (wave >> 1) * 64, wn = (wave & 1) * 32;
    const int sr = tid >> 2, sc = (tid & 3) * 8;

    f32x4 acc[4][2] = {};

    auto compute = [&](int b) {
        const int ko = (lane >> 4) * 8;
        bf16x8 af[4], bfr[2];
#pragma unroll
        for (int i = 0; i < 4; i++)
            af[i] = __builtin_bit_cast(bf16x8, *(const uint4*)&As[b][wm + i * 16 + (lane & 15)][ko]);
#pragma unroll
        for (int j = 0; j < 2; j++)
            bfr[j] = __builtin_bit_cast(bf16x8, *(const uint4*)&Bs[b][wn + j * 16 + (lane & 15)][ko]);
#pragma unroll
        for (int i = 0; i < 4; i++)
#pragma unroll
            for (int j = 0; j < 2; j++)
                acc[i][j] = __builtin_amdgcn_mfma_f32_16x16x32_bf16(af[i], bfr[j], acc[i][j], 0, 0, 0);
    };

    uint4 a0, a1, b0;
    ld(kFrom, a0, a1, b0);
    *(uint4*)&As[0][sr][sc] = a0;
    *(uint4*)&As[0][sr + 64][sc] = a1;
    *(uint4*)&Bs[0][sr][sc] = b0;
    __syncthreads();

    int cur = 0;
    for (int k0 = kFrom + 32; k0 < kTo; k0 += 32) {
        ld(k0, a0, a1, b0);
        compute(cur);
        *(uint4*)&As[cur ^ 1][sr][sc] = a0;
        *(uint4*)&As[cur ^ 1][sr + 64][sc] = a1;
        *(uint4*)&Bs[cur ^ 1][sr][sc] = b0;
        __syncthreads();
        cur ^= 1;
    }
    compute(cur);

    float* Cf = (float*)Cv;
    ushort* Cb = (ushort*)Cv;
#pragma unroll
    for (int i = 0; i < 4; i++) {
#pragma unroll
        for (int j = 0; j < 2; j++) {
            int row = m0 + wm + i * 16 + (lane >> 4) * 4;
            int col = n0 + wn + j * 16 + (lane & 15);
#pragma unroll
            for (int r = 0; r < 4; r++) {
                float val = acc[i][j][r];
                if (bias) val += bias[col];
                if (outbf) Cb[(size_t)(row + r) * ldc + col] = f2bf(val);
                else       Cf[(size_t)(row + r) * ldc + col] = val;
            }
        }
    }
}

// ---------------- k1: z=0 k-GEMM, z=1 v-GEMM (inline f32->bf16), z>=2 Wcat repack ----
__global__ __launch_bounds__(256) void k1_kernel(
    const float* __restrict__ x,
    const float* __restrict__ ke_w, const float* __restrict__ ke_b, ushort* __restrict__ kr,
    const float* __restrict__ ve_w, const float* __restrict__ ve_b, float* __restrict__ v,
    const float* __restrict__ er_w, const float* __restrict__ er_b,
    const float* __restrict__ ad_w, const float* __restrict__ ad_b,
    ushort* __restrict__ wcat)
{
    __shared__ ushort As[2][128][40];
    __shared__ ushort Bs[2][64][40];
    const int z = blockIdx.z;
    const int sr = threadIdx.x >> 2, sc = (threadIdx.x & 3) * 8;

    if (z == 0) {
        const int m0 = blockIdx.y * 128, n0 = blockIdx.x * 64;
        auto ld = [&](int k0, uint4& A0, uint4& A1, uint4& B0) {
            int c0 = k0 + sc, c4 = c0 + 4;
            bool v0 = c0 < C_, v4 = c4 < C_;
            const float* r0 = x + (size_t)(m0 + sr) * IN_;
            const float* r1 = x + (size_t)(m0 + sr + 64) * IN_;
            A0 = pack8(add4(ld4p(r0 + c0, v0), ld4p(r0 + C_ + c0, v0)),
                       add4(ld4p(r0 + c4, v4), ld4p(r0 + C_ + c4, v4)));
            A1 = pack8(add4(ld4p(r1 + c0, v0), ld4p(r1 + C_ + c0, v0)),
                       add4(ld4p(r1 + c4, v4), ld4p(r1 + C_ + c4, v4)));
            const float* rb = ke_w + (size_t)(n0 + sr) * C_;
            B0 = pack8(ld4p(rb + c0, v0), ld4p(rb + c4, v4));
        };
        gemm_core(ld, ke_b, kr, KS, 1, m0, n0, 0, KQ, As, Bs);
    } else if (z == 1) {
        const int m0 = blockIdx.y * 128, n0 = blockIdx.x * 64;
        auto ld = [&](int k0, uint4& A0, uint4& A1, uint4& B0) {
            int c0 = k0 + sc, c4 = c0 + 4;
            bool v0 = c0 < IN_, v4 = c4 < IN_;
            const float* r0 = x + (size_t)(m0 + sr) * IN_;
            const float* r1 = x + (size_t)(m0 + sr + 64) * IN_;
            A0 = pack8(ld4p(r0 + c0, v0), ld4p(r0 + c4, v4));
            A1 = pack8(ld4p(r1 + c0, v0), ld4p(r1 + c4, v4));
            const float* rb = ve_w + (size_t)(n0 + sr) * IN_;
            B0 = pack8(ld4p(rb + c0, v0), ld4p(rb + c4, v4));
        };
        gemm_core(ld, ve_b, v, H_, 0, m0, n0, 0, KX, As, Bs);
    } else {
        int idx = ((z - 2) * 64 + blockIdx.y * 4 + blockIdx.x) * 256 + threadIdx.x;
        if (idx >= 512 * (KBIG / 4)) return;
        int oc = idx / (KBIG / 4), g = idx % (KBIG / 4), c0 = g * 4;
        const float* Wsrc = (oc < 256) ? er_w : ad_w;
        const float* bsrc = (oc < 256) ? er_b : ad_b;
        int oo = oc & 255;
        ushort pk[4];
#pragma unroll
        for (int j = 0; j < 4; j++) {
            int c = c0 + j;
            float val = 0.f;
            if (c < 2048)      { int d = c >> 8, ii = c & 255; val = Wsrc[(size_t)(d * 256 + oo) * 256 + ii]; }
            else if (c < 2056) { val = bsrc[(c - 2048) * 256 + oo]; }
            pk[j] = f2bf(val);
        }
        *(ushort4*)&wcat[(size_t)oc * KBIG + c0] = *(ushort4*)pk;
    }
}

// ---------------- vww: b<32 -> wlog GEMM (km_w inline cvt); else vw fill for n=b-32 ----
__global__ __launch_bounds__(256) void vww_kernel(
    const ushort* __restrict__ kr, const float* __restrict__ v,
    const float* __restrict__ kw2_w, const float* __restrict__ kw2_b,
    const float* __restrict__ km_w, const float* __restrict__ km_b,
    float* __restrict__ wlog, ushort* __restrict__ vw)
{
    __shared__ ushort As[2][128][40];
    __shared__ ushort Bs[2][64][40];
    __shared__ float kf[H_], vl[H_], lg[8], w2l[8];
    const int b = blockIdx.x, t = threadIdx.x;
    const int sr = t >> 2, sc = (t & 3) * 8;

    if (b < 32) {
        const int m0 = (b >> 1) * 128, n0 = (b & 1) * 64;
        auto ld = [&](int k0, uint4& A0, uint4& A1, uint4& B0) {
            A0 = *(const uint4*)&kr[(size_t)(m0 + sr) * KS + k0 + sc];
            A1 = *(const uint4*)&kr[(size_t)(m0 + sr + 64) * KS + k0 + sc];
            int c0 = k0 + sc, c4 = c0 + 4;
            const float* rb = km_w + (size_t)(n0 + sr) * H_;
            B0 = pack8(*(const float4*)(rb + c0), *(const float4*)(rb + c4));
        };
        gemm_core(ld, km_b, wlog, M_, 0, m0, n0, 0, H_, As, Bs);
        return;
    }

    const int n = b - 32;
    if (t < 64) {
        ushort4 u = ((const ushort4*)(kr + (size_t)n * KS))[t];
        kf[t * 4 + 0] = bf2f(u.x); kf[t * 4 + 1] = bf2f(u.y);
        kf[t * 4 + 2] = bf2f(u.z); kf[t * 4 + 3] = bf2f(u.w);
        float4 vv = ((const float4*)(v + (size_t)n * H_))[t];
        vl[t * 4 + 0] = vv.x; vl[t * 4 + 1] = vv.y;
        vl[t * 4 + 2] = vv.z; vl[t * 4 + 3] = vv.w;
    }
    __syncthreads();
    {
        int d = t >> 5, l = t & 31;
        float acc = 0.f;
        const float* wr = kw2_w + d * H_;
#pragma unroll
        for (int s = 0; s < 8; s++) acc += kf[l + 32 * s] * wr[l + 32 * s];
#pragma unroll
        for (int off = 16; off; off >>= 1) acc += __shfl_xor(acc, off);
        if (l == 0) lg[d] = acc + kw2_b[d];
    }
    __syncthreads();
    if (t < 8) {
        float val = lg[t];
        float mx = val;
#pragma unroll
        for (int off = 1; off < 8; off <<= 1) mx = fmaxf(mx, __shfl_xor(mx, off));
        float e = expf(val - mx), s = e;
#pragma unroll
        for (int off = 1; off < 8; off <<= 1) s += __shfl_xor(s, off);
        w2l[t] = e / s;
    }
    __syncthreads();
    ushort* row = vw + (size_t)n * KBIG;
    for (int g = t; g < KBIG / 4; g += 256) {
        int c0 = g * 4;
        ushort pk[4];
#pragma unroll
        for (int j = 0; j < 4; j++) {
            int c = c0 + j;
            float val = 0.f;
            if (c < 2048)      val = w2l[c >> 8] * vl[c & 255];
            else if (c < 2056) val = w2l[c - 2048];
            pk[j] = f2bf(val);
        }
        *(ushort4*)&row[c0] = *(ushort4*)pk;
    }
}

// ---------------- bigw: big expert GEMM, K split x NZ ----------------
__global__ __launch_bounds__(256) void bigw_kernel(
    const ushort* __restrict__ vw, const ushort* __restrict__ Wcat,
    float* __restrict__ parts)
{
    __shared__ ushort As[2][128][40];
    __shared__ ushort Bs[2][64][40];
    const int z = blockIdx.z;
    const int m0 = blockIdx.y * 128, n0 = blockIdx.x * 64;
    const int sr = threadIdx.x >> 2, sc = (threadIdx.x & 3) * 8;
    auto ld = [&](int k0, uint4& A0, uint4& A1, uint4& B0) {
        A0 = *(const uint4*)&vw[(size_t)(m0 + sr) * KBIG + k0 + sc];
        A1 = *(const uint4*)&vw[(size_t)(m0 + sr + 64) * KBIG + k0 + sc];
        B0 = *(const uint4*)&Wcat[(size_t)(n0 + sr) * KBIG + k0 + sc];
    };
    gemm_core(ld, nullptr, parts + (size_t)z * N_ * 512, 512, 0,
              m0, n0, z * KSPL, (z + 1) * KSPL, As, Bs);
}

// ---------------- streaming memory pass: global_load_lds DMA pipeline ----------------
// grid 8192: block = (n, quarter of 64 rows). 4 waves; wave owns 16 rows (8KB),
// DMA'd as 8 x 1KB global_load_lds chunks issued upfront (8KB in flight/wave).
// Consume with constant s_waitcnt vmcnt(7) (in-order retirement => oldest chunk
// complete; never drained to 0). FMA from LDS, NT store, register dot-partials,
// shuffle-reduce epilogue.
__global__ __launch_bounds__(256) void mem_stream_kernel(
    const float* __restrict__ mem_in,
    const float* __restrict__ wlog,        // N x 128 logits
    const float* __restrict__ parts,       // NZ x N x 512
    float* __restrict__ mem_out,
    ushort* __restrict__ kr)
{
    __shared__ float ring[4][2048];        // 4 waves x 8KB
    __shared__ float wl[M_];
    __shared__ float el[64], al[64];
    __shared__ float red[4];
    const int n = blockIdx.x >> 2, q = blockIdx.x & 3, hbase = q * 64;
    const int t = threadIdx.x;

    // prologue: waves 0-1 -> e/a for this block's 64 rows; waves 2-3 -> softmax(wlog[n])
    float lv = 0.f;
    if (t < 128) {
        int isA = t >> 6, tt = t & 63;
        int col = isA * 256 + hbase + tt;
        float pacc = 0.f;
#pragma unroll
        for (int z = 0; z < NZ; z++)
            pacc += parts[(size_t)z * N_ * 512 + (size_t)n * 512 + col];
        if (isA) al[tt] = tanhf(pacc);
        else     el[tt] = 1.f / (1.f + expf(-pacc));
    } else {
        int tt = t - 128;
        lv = wlog[(size_t)n * M_ + tt];
        float mx = lv;
#pragma unroll
        for (int off = 32; off; off >>= 1) mx = fmaxf(mx, __shfl_xor(mx, off));
        if ((t & 63) == 0) red[(t >> 6) - 2] = mx;
    }
    __syncthreads();
    if (t >= 128) {
        int tt = t - 128;
        float gmax = fmaxf(red[0], red[1]);
        float ev = expf(lv - gmax);
        float s = ev;
#pragma unroll
        for (int off = 32; off; off >>= 1) s += __shfl_xor(s, off);
        if ((t & 63) == 0) red[2 + (t >> 6) - 2] = s;
        wl[tt] = ev;
    }
    __syncthreads();
    if (t >= 128) wl[t - 128] *= 1.f / (red[2] + red[3]);
    __syncthreads();

    const int wave = t >> 6, lane = t & 63;
    const int l32 = lane & 31, hi = lane >> 5;
    const int rowg0 = hbase + wave * 16;       // wave's first global row
    const float* gsrc = mem_in + ((size_t)n * H_ + rowg0) * M_;
    float* gdst = mem_out + ((size_t)n * H_ + rowg0) * M_;
    float* lbase = ring[wave];

    // issue all 8 chunks: chunk c = rows c*2, c*2+1 (1KB), lane l -> 16B at l*16
#pragma unroll
    for (int c = 0; c < 8; c++) {
        __builtin_amdgcn_global_load_lds(
            (gas_t)(const void*)(gsrc + c * 256 + lane * 4),
            (las_t)(void*)(lbase + c * 256),
            16, 0, 0);
    }

    f32x4 wv = ((const f32x4*)wl)[l32];
    float racc[8];
#pragma unroll
    for (int c = 0; c < 8; c++) {
        asm volatile("s_waitcnt vmcnt(7)" ::: "memory");   // oldest chunk (c) complete
        __builtin_amdgcn_sched_barrier(0);
        f32x4 mv = *(const f32x4*)&lbase[c * 256 + lane * 4];
        int rloc = c * 2 + hi;                              // 0..15 within wave
        float eh = el[wave * 16 + rloc], ah = al[wave * 16 + rloc];
        f32x4 nv = mv * (1.f - wv * eh) + wv * ah;
        __builtin_nontemporal_store(nv, (f32x4*)(gdst + c * 256 + lane * 4));
        racc[c] = mv[0] * wv[0] + mv[1] * wv[1] + mv[2] * wv[2] + mv[3] * wv[3];
    }

    // epilogue: 8 independent 32-lane reductions
#pragma unroll
    for (int c = 0; c < 8; c++) {
        float r = racc[c];
#pragma unroll
        for (int off = 1; off < 32; off <<= 1) r += __shfl_xor(r, off);
        if (l32 == 0)
            kr[(size_t)n * KS + H_ + rowg0 + c * 2 + hi] = f2bf(r);
    }
}

// ---------------- fy: f = tanh(kr @ sum_w.T + sum_b) fused into y ----------------
__global__ __launch_bounds__(256) void fy_kernel(
    const ushort* __restrict__ kr, const float* __restrict__ sum_w,
    const float* __restrict__ sum_b, const float* __restrict__ out_w,
    const float* __restrict__ out_b, float* __restrict__ y)
{
    __shared__ ushort As[2][64][40];
    __shared__ ushort Bs[2][256][40];
    __shared__ float yl[64][4];
    const int tid = threadIdx.x, lane = tid & 63, wave = tid >> 6;
    const int wn = wave * 64;
    const int m0 = blockIdx.x * 64;
    const int sr = tid >> 2, sc = (tid & 3) * 8;

    f32x4 acc[4][4] = {};

    auto compute = [&](int b) {
        const int ko = (lane >> 4) * 8;
        bf16x8 af[4], bfr[4];
#pragma unroll
        for (int i = 0; i < 4; i++)
            af[i] = __builtin_bit_cast(bf16x8, *(const uint4*)&As[b][i * 16 + (lane & 15)][ko]);
#pragma unroll
        for (int j = 0; j < 4; j++)
            bfr[j] = __builtin_bit_cast(bf16x8, *(const uint4*)&Bs[b][wn + j * 16 + (lane & 15)][ko]);
#pragma unroll
        for (int i = 0; i < 4; i++)
#pragma unroll
            for (int j = 0; j < 4; j++)
                acc[i][j] = __builtin_amdgcn_mfma_f32_16x16x32_bf16(af[i], bfr[j], acc[i][j], 0, 0, 0);
    };

    auto stage = [&](int buf, int k0) {
        int c0 = k0 + sc, c4 = c0 + 4;
        *(uint4*)&As[buf][sr][sc] = *(const uint4*)&kr[(size_t)(m0 + sr) * KS + k0 + sc];
#pragma unroll
        for (int g = 0; g < 4; g++) {
            const float* rb = sum_w + (size_t)(sr + g * 64) * KS;
            *(uint4*)&Bs[buf][sr + g * 64][sc] = pack8(*(const float4*)(rb + c0), *(const float4*)(rb + c4));
        }
    };

    stage(0, 0);
    __syncthreads();
    int cur = 0;
    for (int k0 = 32; k0 < KS; k0 += 32) {
        compute(cur);
        stage(cur ^ 1, k0);
        __syncthreads();
        cur ^= 1;
    }
    compute(cur);

    float ow[4], sb[4];
#pragma unroll
    for (int j = 0; j < 4; j++) {
        int col = wn + j * 16 + (lane & 15);
        ow[j] = out_w[col];
        sb[j] = sum_b[col];
    }
    float yp[4][4];
#pragma unroll
    for (int i = 0; i < 4; i++)
#pragma unroll
        for (int r = 0; r < 4; r++) {
            float s = 0.f;
#pragma unroll
            for (int j = 0; j < 4; j++)
                s += tanhf(acc[i][j][r] + sb[j]) * ow[j];
            yp[i][r] = s;
        }
#pragma unroll
    for (int off = 1; off < 16; off <<= 1)
#pragma unroll
        for (int i = 0; i < 4; i++)
#pragma unroll
            for (int r = 0; r < 4; r++)
                yp[i][r] += __shfl_xor(yp[i][r], off);
    if ((lane & 15) == 0) {
#pragma unroll
        for (int i = 0; i < 4; i++)
#pragma unroll
            for (int r = 0; r < 4; r++)
                yl[i * 16 + (lane >> 4) * 4 + r][wave] = yp[i][r];
    }
    __syncthreads();
    if (tid < 64)
        y[m0 + tid] = yl[tid][0] + yl[tid][1] + yl[tid][2] + yl[tid][3] + out_b[0];
}

extern "C" void kernel_launch(void* const* d_in, const int* in_sizes, int n_in,
                              void* d_out, int out_size, void* d_ws, size_t ws_size,
                              hipStream_t stream) {
    const float* x      = (const float*)d_in[0];
    const float* mem_in = (const float*)d_in[1];
    const float* ke_w   = (const float*)d_in[2];
    const float* ke_b   = (const float*)d_in[3];
    const float* km_w   = (const float*)d_in[4];
    const float* km_b   = (const float*)d_in[5];
    const float* kw2_w  = (const float*)d_in[6];
    const float* kw2_b  = (const float*)d_in[7];
    const float* sum_w  = (const float*)d_in[8];
    const float* sum_b  = (const float*)d_in[9];
    const float* out_w  = (const float*)d_in[10];
    const float* out_b  = (const float*)d_in[11];
    const float* ve_w   = (const float*)d_in[12];
    const float* ve_b   = (const float*)d_in[13];
    const float* er_w   = (const float*)d_in[14];
    const float* er_b   = (const float*)d_in[15];
    const float* ad_w   = (const float*)d_in[16];
    const float* ad_b   = (const float*)d_in[17];

    float* y_out   = (float*)d_out;
    float* mem_out = (float*)d_out + N_;

    // ---- workspace (float units, 16B-aligned offsets), ~41 MB ----
    float* ws = (float*)d_ws;
    size_t o = 0;
    float*  parts = ws + o;            o += (size_t)NZ * N_ * 512;      // 6,291,456
    ushort* vw    = (ushort*)(ws + o); o += (size_t)N_ * KBIG / 2;      // 2,162,688
    ushort* Wcat  = (ushort*)(ws + o); o += (size_t)512 * KBIG / 2;     //   540,672
    ushort* kr    = (ushort*)(ws + o); o += (size_t)N_ * KS / 2;        //   524,288
    float*  v     = ws + o;            o += (size_t)N_ * H_;            //   524,288
    float*  wlog  = ws + o;            o += (size_t)N_ * M_;            //   262,144

    // 1. k-GEMM (z=0) + v-GEMM (z=1) + Wcat repack (z=2..18), inline f32->bf16
    k1_kernel<<<dim3(4, 16, 19), 256, 0, stream>>>(
        x, ke_w, ke_b, kr, ve_w, ve_b, v, er_w, er_b, ad_w, ad_b, Wcat);
    // 2. wlog GEMM (b<32) + w2/vw fill (b>=32)
    vww_kernel<<<32 + N_, 256, 0, stream>>>(
        kr, v, kw2_w, kw2_b, km_w, km_b, wlog, vw);
    // 3. big expert GEMM, K split x6 -> 768 blocks
    bigw_kernel<<<dim3(8, 16, NZ), 256, 0, stream>>>(vw, Wcat, parts);
    // 4. streaming memory pass: global_load_lds DMA pipeline, counted vmcnt
    mem_stream_kernel<<<4 * N_, 256, 0, stream>>>(mem_in, wlog, parts, mem_out, kr);
    // 5. f GEMM fused with y reduction
    fy_kernel<<<N_ / 64, 256, 0, stream>>>(kr, sum_w, sum_b, out_w, out_b, y_out);
}